// Round 16
// baseline (240.497 us; speedup 1.0000x reference)
//
#include <hip/hip_runtime.h>

#define DEV __device__ __forceinline__

typedef __attribute__((ext_vector_type(4))) float f32x4;
typedef __attribute__((ext_vector_type(8))) short short8;
typedef __attribute__((ext_vector_type(8))) __bf16 bf16x8;

DEV unsigned short f2bf(float f) {
  __bf16 h = (__bf16)f;
  return __builtin_bit_cast(unsigned short, h);
}
DEV unsigned pack2(float a, float b) {
  return (unsigned)f2bf(a) | ((unsigned)f2bf(b) << 16);
}
DEV bf16x8 ld_bf8(const unsigned short* p) {
  short8 v = *(const short8*)p;
  return __builtin_bit_cast(bf16x8, v);
}
DEV f32x4 MFMA(bf16x8 a, bf16x8 b, f32x4 c) {
  return __builtin_amdgcn_mfma_f32_16x16x32_bf16(a, b, c, 0, 0, 0);
}

typedef const __attribute__((address_space(1))) void GV;
typedef __attribute__((address_space(3))) void LV;
DEV void gl_lds16(const void* g, void* l) {
  __builtin_amdgcn_global_load_lds((GV*)g, (LV*)l, 16, 0, 0);
}

// XCD-chunked bijective block swizzle (T1). Requires nwg % 8 == 0.
DEV void xcd_decode(int gx, int& bx, int& by) {
  const int nwg = gridDim.x, bid = blockIdx.x;
  const int cpx = nwg >> 3;
  const int swz = (bid & 7) * cpx + (bid >> 3);
  by = swz / gx;
  bx = swz % gx;
}

// ---------------- LayerNorm (fp32 in -> bf16 out), one row per block ----------
__global__ void __launch_bounds__(256) ln_fused(
    const float* __restrict__ x, const float* __restrict__ g,
    const float* __restrict__ b, unsigned short* __restrict__ y)
{
  const int row = blockIdx.x, tid = threadIdx.x;
  const float4 xv = ((const float4*)(x + (size_t)row * 1024))[tid];
  float s  = xv.x + xv.y + xv.z + xv.w;
  float s2 = xv.x * xv.x + xv.y * xv.y + xv.z * xv.z + xv.w * xv.w;
#pragma unroll
  for (int o = 32; o > 0; o >>= 1) { s += __shfl_down(s, o); s2 += __shfl_down(s2, o); }
  __shared__ float ps[4], ps2[4];
  if ((tid & 63) == 0) { ps[tid >> 6] = s; ps2[tid >> 6] = s2; }
  __syncthreads();
  float S  = ps[0] + ps[1] + ps[2] + ps[3];
  float S2 = ps2[0] + ps2[1] + ps2[2] + ps2[3];
  float mu = S * (1.f / 1024.f);
  float rs = rsqrtf(S2 * (1.f / 1024.f) - mu * mu + 1e-5f);
  const float4 gv = ((const float4*)g)[tid];
  const float4 bv = ((const float4*)b)[tid];
  uint2 r;
  r.x = pack2((xv.x - mu) * rs * gv.x + bv.x, (xv.y - mu) * rs * gv.y + bv.y);
  r.y = pack2((xv.z - mu) * rs * gv.z + bv.z, (xv.w - mu) * rs * gv.w + bv.w);
  ((uint2*)(y + (size_t)row * 1024))[tid] = r;
}

// ---------------- generic transpose fp32 [R][C] -> bf16 [C][R] ----------------
__global__ void __launch_bounds__(256) transp_f2b(
    const float* __restrict__ src, unsigned short* __restrict__ dst, int R, int C)
{
  __shared__ float t[64][65];
  const int c0 = blockIdx.x * 64, r0 = blockIdx.y * 64;
  const int tx = threadIdx.x & 63, tq = threadIdx.x >> 6;
#pragma unroll
  for (int i = 0; i < 16; i++) {
    int r = tq * 16 + i;
    t[r][tx] = src[(size_t)(r0 + r) * C + c0 + tx];
  }
  __syncthreads();
#pragma unroll
  for (int i = 0; i < 16; i++) {
    int c = tq * 16 + i;
    dst[(size_t)(c0 + c) * R + r0 + tx] = f2bf(t[tx][c]);
  }
}

// ------- wq/wk/wv [H][C][64] fp32 -> wqkvT [3*1024][1024] bf16 ([n][k]) -------
__global__ void __launch_bounds__(256) qkv_transp(
    const float* __restrict__ wq, const float* __restrict__ wk,
    const float* __restrict__ wv, unsigned short* __restrict__ dst)
{
  __shared__ float t[64][65];
  const int c0 = blockIdx.x * 64, h = blockIdx.y, z = blockIdx.z;
  const float* w = (z == 0 ? wq : z == 1 ? wk : wv) + (size_t)h * 1024 * 64;
  const int tx = threadIdx.x & 63, tq = threadIdx.x >> 6;
#pragma unroll
  for (int i = 0; i < 16; i++) {
    int c = tq * 16 + i;
    t[c][tx] = w[(size_t)(c0 + c) * 64 + tx];
  }
  __syncthreads();
  unsigned short* drow = dst + (size_t)(z * 1024 + h * 64) * 1024 + c0;
#pragma unroll
  for (int i = 0; i < 16; i++) {
    int d = tq * 16 + i;
    drow[(size_t)d * 1024 + tx] = f2bf(t[tx][d]);
  }
}

// ------- V section of qkv [4096][3072] -> vt [B*H][64][2048] (d-major) -------
__global__ void __launch_bounds__(256) v_transp(
    const unsigned short* __restrict__ qkv, unsigned short* __restrict__ vt)
{
  __shared__ unsigned s[64][65];
  const int t0 = blockIdx.x * 64, h = blockIdx.y, b = blockIdx.z;
  const int tx = threadIdx.x & 63, tq = threadIdx.x >> 6;
#pragma unroll
  for (int i = 0; i < 16; i++) {
    int tr = tq * 16 + i;
    s[tr][tx] = qkv[(size_t)(b * 2048 + t0 + tr) * 3072 + 2048 + h * 64 + tx];
  }
  __syncthreads();
  unsigned short* vb = vt + (size_t)((b * 16 + h) * 64) * 2048 + t0;
#pragma unroll
  for (int i = 0; i < 16; i++) {
    int d = tq * 16 + i;
    vb[(size_t)d * 2048 + tx] = (unsigned short)s[tx][d];
  }
}

// ---------------- GEMM 128x128, BK=32, TRIPLE-buffer, counted vmcnt -----------
// T3/T4: raw s_barrier + s_waitcnt vmcnt(4) keeps the next tile's 4 loads in
// flight across the barrier (HIP __syncthreads would drain vmcnt(0)).
// Safety: stage(t+2) overwrites tile t-1's slot; all waves passed the barrier
// only after compute(t-1) (ds_reads consumed by MFMAs before barrier).
template<int BIAS, int RELU, int RES, int OBF>
__global__ void __launch_bounds__(256) gemm_bt(
    const unsigned short* __restrict__ A, const unsigned short* __restrict__ Bt,
    const float* __restrict__ bias, const float* __restrict__ res,
    void* __restrict__ out, int M, int N, int K, int gx)
{
  __shared__ unsigned short As[3][128 * 32];
  __shared__ unsigned short Bs[3][128 * 32];
  int bx, by;
  xcd_decode(gx, bx, by);
  const int tid = threadIdx.x;
  const int wid = tid >> 6, lane = tid & 63;
  const int lg = lane >> 4, lr = lane & 15;
  const int m0 = by * 128, n0 = bx * 128;
  const int wr = (wid >> 1) * 64, wc = (wid & 1) * 64;

  const int srow = tid >> 2;
  const int scs = (tid & 3) ^ (srow & 3);
  const unsigned short* ga = A + (size_t)(m0 + srow) * K + scs * 8;
  const unsigned short* gb = Bt + (size_t)(n0 + srow) * K + scs * 8;
  const int ca = (lg ^ (lr & 3)) * 8;

  f32x4 acc[4][4] = {};

  auto stage = [&](int buf, int k0) {
    char* asb = (char*)&As[buf][0] + wid * 1024;
    char* bsb = (char*)&Bs[buf][0] + wid * 1024;
    gl_lds16(ga + k0, asb);
    gl_lds16(ga + k0 + (size_t)64 * K, asb + 4096);
    gl_lds16(gb + k0, bsb);
    gl_lds16(gb + k0 + (size_t)64 * K, bsb + 4096);
  };

  const int nt = K >> 5;
  stage(0, 0);
  if (nt > 1) stage(1, 32);
  for (int t = 0; t < nt; t++) {
    if (t + 1 < nt) { asm volatile("s_waitcnt vmcnt(4)" ::: "memory"); }
    else            { asm volatile("s_waitcnt vmcnt(0)" ::: "memory"); }
    __builtin_amdgcn_s_barrier();
    if (t + 2 < nt) stage((t + 2) % 3, (t + 2) * 32);
    const int cur = t % 3;
    bf16x8 a[4], b[4];
#pragma unroll
    for (int m = 0; m < 4; m++) a[m] = ld_bf8(&As[cur][(wr + m * 16 + lr) * 32 + ca]);
#pragma unroll
    for (int n = 0; n < 4; n++) b[n] = ld_bf8(&Bs[cur][(wc + n * 16 + lr) * 32 + ca]);
#pragma unroll
    for (int m = 0; m < 4; m++)
#pragma unroll
      for (int n = 0; n < 4; n++)
        acc[m][n] = MFMA(a[m], b[n], acc[m][n]);
  }

#pragma unroll
  for (int m = 0; m < 4; m++) {
    const int row0 = m0 + wr + m * 16 + lg * 4;
#pragma unroll
    for (int n = 0; n < 4; n++) {
      const int col = n0 + wc + n * 16 + lr;
      const float bv = BIAS ? bias[col] : 0.f;
#pragma unroll
      for (int r = 0; r < 4; r++) {
        const size_t off = (size_t)(row0 + r) * N + col;
        float v = acc[m][n][r] + bv;
        if (RES) v += res[off];
        if (RELU) v = v > 0.f ? v : 0.f;
        if (OBF) ((unsigned short*)out)[off] = f2bf(v);
        else     ((float*)out)[off] = v;
      }
    }
  }
}

// ---------------- GEMM 64x64, BK=64, dbuf, XOR-swizzled (occupancy: 4/CU) -----
template<int BIAS, int RELU, int RES, int OBF>
__global__ void __launch_bounds__(256) gemm_64(
    const unsigned short* __restrict__ A, const unsigned short* __restrict__ Bt,
    const float* __restrict__ bias, const float* __restrict__ res,
    void* __restrict__ out, int M, int N, int K, int gx)
{
  __shared__ unsigned short As[2][64 * 64];
  __shared__ unsigned short Bs[2][64 * 64];
  int bx, by;
  xcd_decode(gx, bx, by);
  const int tid = threadIdx.x;
  const int wid = tid >> 6, lane = tid & 63;
  const int lg = lane >> 4, lr = lane & 15;
  const int m0 = by * 64, n0 = bx * 64;
  const int wr = (wid >> 1) * 32, wc = (wid & 1) * 32;

  const int srow = tid >> 3;
  const int scs = (tid & 7) ^ (srow & 7);
  const unsigned short* ga = A + (size_t)(m0 + srow) * K + scs * 8;
  const unsigned short* gb = Bt + (size_t)(n0 + srow) * K + scs * 8;
  const int lxs = lr & 7;

  f32x4 acc[2][2] = {};

  auto stage = [&](int buf, int k0) {
    char* asb = (char*)&As[buf][0] + wid * 1024;
    char* bsb = (char*)&Bs[buf][0] + wid * 1024;
    gl_lds16(ga + k0, asb);
    gl_lds16(ga + k0 + (size_t)32 * K, asb + 4096);
    gl_lds16(gb + k0, bsb);
    gl_lds16(gb + k0 + (size_t)32 * K, bsb + 4096);
  };

  stage(0, 0);
  int cur = 0;
  for (int k0 = 0; k0 < K; k0 += 64) {
    __syncthreads();
    if (k0 + 64 < K) stage(cur ^ 1, k0 + 64);
#pragma unroll
    for (int kk = 0; kk < 2; kk++) {
      const int cb = kk * 4;
      bf16x8 a[2], b[2];
#pragma unroll
      for (int m = 0; m < 2; m++)
        a[m] = ld_bf8(&As[cur][(wr + m * 16 + lr) * 64 + ((cb + lg) ^ lxs) * 8]);
#pragma unroll
      for (int n = 0; n < 2; n++)
        b[n] = ld_bf8(&Bs[cur][(wc + n * 16 + lr) * 64 + ((cb + lg) ^ lxs) * 8]);
#pragma unroll
      for (int m = 0; m < 2; m++)
#pragma unroll
        for (int n = 0; n < 2; n++)
          acc[m][n] = MFMA(a[m], b[n], acc[m][n]);
    }
    cur ^= 1;
  }

#pragma unroll
  for (int m = 0; m < 2; m++) {
    const int row0 = m0 + wr + m * 16 + lg * 4;
#pragma unroll
    for (int n = 0; n < 2; n++) {
      const int col = n0 + wc + n * 16 + lr;
      const float bv = BIAS ? bias[col] : 0.f;
#pragma unroll
      for (int r = 0; r < 4; r++) {
        const size_t off = (size_t)(row0 + r) * N + col;
        float v = acc[m][n][r] + bv;
        if (RES) v += res[off];
        if (RELU) v = v > 0.f ? v : 0.f;
        if (OBF) ((unsigned short*)out)[off] = f2bf(v);
        else     ((float*)out)[off] = v;
      }
    }
  }
}

// ---------------- causal flash attention (fixed-shift softmax) ----------------
__global__ void __launch_bounds__(256) attn_fwd(
    const unsigned short* __restrict__ qkv, const unsigned short* __restrict__ vt,
    unsigned short* __restrict__ out)
{
  __shared__ unsigned short Ks[2][64 * 64];
  __shared__ unsigned short Vs[2][64 * 64];
  __shared__ unsigned short PA[4][16][72];
  __shared__ unsigned short PB[4][16][72];

  int j, bh;
  xcd_decode(16, j, bh);          // 4 heads per XCD (K/V L2-local)
  const int b = bh >> 4, h = bh & 15;
  const int tid = threadIdx.x, wid = tid >> 6, lane = tid & 63;
  const int lg = lane >> 4, lr = lane & 15;

  const int tA = j, tB = 31 - j;
  const int nkt = tB + 1;
  const float C2 = 0.18033688f;        // 0.125 * log2(e)

  const unsigned short* kbase = qkv + (size_t)(b * 2048) * 3072 + 1024 + h * 64;
  const unsigned short* vbase = vt + (size_t)(bh * 64) * 2048;

  const int sr = tid >> 3;
  const int sc = tid & 7;
  const int c0 = sc ^ (sr & 7);

  auto stage = [&](int buf, int kt) {
    const int kv0 = kt * 64;
    char* kd = (char*)&Ks[buf][0] + wid * 1024;
    char* vd = (char*)&Vs[buf][0] + wid * 1024;
    gl_lds16(kbase + (size_t)(kv0 + sr) * 3072 + c0 * 8, kd);
    gl_lds16(kbase + (size_t)(kv0 + 32 + sr) * 3072 + c0 * 8, kd + 4096);
    gl_lds16(vbase + (size_t)sr * 2048 + kv0 + c0 * 8, vd);
    gl_lds16(vbase + (size_t)(32 + sr) * 2048 + kv0 + c0 * 8, vd + 4096);
  };

  auto process = [&](int kt, int qt, const bf16x8& qf0, const bf16x8& qf1,
                     f32x4 (&o)[4], float& l, int buf, unsigned short* Pr) {
    const int kv0 = kt * 64;
    const int qg = qt * 64 + wid * 16 + lr;
    const unsigned short* Kb = &Ks[buf][0];
    const unsigned short* Vb = &Vs[buf][0];
    f32x4 s[4] = {};
    __builtin_amdgcn_s_setprio(1);
#pragma unroll
    for (int f = 0; f < 4; f++) {
      const int row = f * 16 + lr;
      const int rc = row & 7;
      s[f] = MFMA(ld_bf8(Kb + row * 64 + (lg ^ rc) * 8), qf0, s[f]);
      s[f] = MFMA(ld_bf8(Kb + row * 64 + ((lg | 4) ^ rc) * 8), qf1, s[f]);
    }
    __builtin_amdgcn_s_setprio(0);
    float p[16];
    const bool diag = (kt == qt);
    float ps = 0.f;
#pragma unroll
    for (int f = 0; f < 4; f++)
#pragma unroll
      for (int r = 0; r < 4; r++) {
        float sv = s[f][r];
        if (diag) {
          const int kv = kv0 + f * 16 + lg * 4 + r;
          sv = (kv <= qg) ? sv : -1e30f;
        }
        const float pv = exp2f(sv * C2);   // fixed-shift softmax numerator
        p[f * 4 + r] = pv;
        ps += pv;
      }
    l += ps;                               // lane-partial; reduced at epilogue
#pragma unroll
    for (int f = 0; f < 4; f++) {
      *(unsigned*)(Pr + f * 16 + lg * 4)     = pack2(p[f * 4 + 0], p[f * 4 + 1]);
      *(unsigned*)(Pr + f * 16 + lg * 4 + 2) = pack2(p[f * 4 + 2], p[f * 4 + 3]);
    }
    const bf16x8 pf0 = ld_bf8(Pr + lg * 8);
    const bf16x8 pf1 = ld_bf8(Pr + 32 + lg * 8);
    __builtin_amdgcn_s_setprio(1);
#pragma unroll
    for (int df = 0; df < 4; df++) {
      const int row = df * 16 + lr;
      const int rc = row & 7;
      o[df] = MFMA(ld_bf8(Vb + row * 64 + (lg ^ rc) * 8), pf0, o[df]);
      o[df] = MFMA(ld_bf8(Vb + row * 64 + ((lg | 4) ^ rc) * 8), pf1, o[df]);
    }
    __builtin_amdgcn_s_setprio(0);
  };

  const unsigned short* qb = qkv + (size_t)(b * 2048) * 3072 + h * 64;
  const int qrA = tA * 64 + wid * 16 + lr;
  const int qrB = tB * 64 + wid * 16 + lr;
  const bf16x8 qA0 = ld_bf8(qb + (size_t)qrA * 3072 + lg * 8);
  const bf16x8 qA1 = ld_bf8(qb + (size_t)qrA * 3072 + 32 + lg * 8);
  const bf16x8 qB0 = ld_bf8(qb + (size_t)qrB * 3072 + lg * 8);
  const bf16x8 qB1 = ld_bf8(qb + (size_t)qrB * 3072 + 32 + lg * 8);

  f32x4 oA[4] = {}, oB[4] = {};
  float lA = 0.f, lB = 0.f;

  stage(0, 0);
  __syncthreads();
  for (int kt = 0; kt < nkt; kt++) {
    const int buf = kt & 1;
    if (kt + 1 < nkt) stage(buf ^ 1, kt + 1);
    if (kt <= tA) process(kt, tA, qA0, qA1, oA, lA, buf, &PA[wid][lr][0]);
    process(kt, tB, qB0, qB1, oB, lB, buf, &PB[wid][lr][0]);
    __syncthreads();
  }

  lA += __shfl_xor(lA, 16); lA += __shfl_xor(lA, 32);
  lB += __shfl_xor(lB, 16); lB += __shfl_xor(lB, 32);
  const float invA = 1.f / lA, invB = 1.f / lB;
  {
    const int qg = tA * 64 + wid * 16 + lr;
    unsigned* orow = (unsigned*)(out + (size_t)(b * 2048 + qg) * 1024 + h * 64 + lg * 4);
#pragma unroll
    for (int df = 0; df < 4; df++) {
      orow[df * 8 + 0] = pack2(oA[df][0] * invA, oA[df][1] * invA);
      orow[df * 8 + 1] = pack2(oA[df][2] * invA, oA[df][3] * invA);
    }
  }
  {
    const int qg = tB * 64 + wid * 16 + lr;
    unsigned* orow = (unsigned*)(out + (size_t)(b * 2048 + qg) * 1024 + h * 64 + lg * 4);
#pragma unroll
    for (int df = 0; df < 4; df++) {
      orow[df * 8 + 0] = pack2(oB[df][0] * invB, oB[df][1] * invB);
      orow[df * 8 + 1] = pack2(oB[df][2] * invB, oB[df][3] * invB);
    }
  }
}

// ------------------------------------------------------------------------------
extern "C" void kernel_launch(void* const* d_in, const int* in_sizes, int n_in,
                              void* d_out, int out_size, void* d_ws, size_t ws_size,
                              hipStream_t stream)
{
  const float* x     = (const float*)d_in[0];
  const float* wq    = (const float*)d_in[1];
  const float* wk    = (const float*)d_in[2];
  const float* wv    = (const float*)d_in[3];
  const float* wproj = (const float*)d_in[4];
  const float* bproj = (const float*)d_in[5];
  const float* gln1  = (const float*)d_in[6];
  const float* bln1  = (const float*)d_in[7];
  const float* gln2  = (const float*)d_in[8];
  const float* bln2  = (const float*)d_in[9];
  const float* wff1  = (const float*)d_in[10];
  const float* bff1  = (const float*)d_in[11];
  const float* wff2  = (const float*)d_in[12];
  const float* bff2  = (const float*)d_in[13];

  char* ws = (char*)d_ws;
  const size_t MB = 1u << 20;
  float*          x2    = (float*)         (ws + 0 * MB);   // 16 MB
  unsigned short* hbuf  = (unsigned short*)(ws + 16 * MB);  //  8 MB
  unsigned short* xn1   = (unsigned short*)(ws + 24 * MB);  //  8 MB (reused by attn out)
  unsigned short* attn  = (unsigned short*)(ws + 24 * MB);
  unsigned short* qkvb  = (unsigned short*)(ws + 32 * MB);  // 24 MB
  unsigned short* vtb   = (unsigned short*)(ws + 56 * MB);  //  8 MB
  unsigned short* a1    = (unsigned short*)(ws + 32 * MB);  // 32 MB (over dead qkv+vt)
  unsigned short* wqkvT = (unsigned short*)(ws + 64 * MB);  //  6 MB
  unsigned short* wprojT= (unsigned short*)(ws + 70 * MB);  //  2 MB
  unsigned short* wff1T = (unsigned short*)(ws + 72 * MB);  //  8 MB
  unsigned short* wff2T = (unsigned short*)(ws + 80 * MB);  //  8 MB  (total 88 MB)

  // weight preprocessing (fp32 -> bf16, transposed to [N][K])
  qkv_transp<<<dim3(16, 16, 3), 256, 0, stream>>>(wq, wk, wv, wqkvT);
  transp_f2b<<<dim3(16, 16), 256, 0, stream>>>(wproj, wprojT, 1024, 1024);
  transp_f2b<<<dim3(64, 16), 256, 0, stream>>>(wff1, wff1T, 1024, 4096);
  transp_f2b<<<dim3(16, 64), 256, 0, stream>>>(wff2, wff2T, 4096, 1024);

  // x -> LN1 -> xn1 (bf16)
  ln_fused<<<4096, 256, 0, stream>>>(x, gln1, bln1, xn1);
  // QKV = xn1 @ wqkvT : [4096][3072] bf16   (grid 24x32 = 768)
  gemm_bt<0, 0, 0, 1><<<768, 256, 0, stream>>>(
      xn1, wqkvT, nullptr, nullptr, qkvb, 4096, 3072, 1024, 24);
  // V -> d-major
  v_transp<<<dim3(32, 16, 2), 256, 0, stream>>>(qkvb, vtb);
  // attention -> attn (bf16 [4096][1024])  (grid 512, diagonal-paired)
  attn_fwd<<<512, 256, 0, stream>>>(qkvb, vtb, attn);
  // x2 = attn @ wprojT + bproj + x   (fp32)  (grid 16x64 = 1024)
  gemm_64<1, 0, 1, 0><<<1024, 256, 0, stream>>>(
      attn, wprojT, bproj, x, x2, 4096, 1024, 1024, 16);
  // h = LN2(x2) (bf16)
  ln_fused<<<4096, 256, 0, stream>>>(x2, gln2, bln2, hbuf);
  // a1 = relu(h @ wff1T + bff1)  (bf16 [4096][4096])  (grid 32x32 = 1024)
  gemm_bt<1, 1, 0, 1><<<1024, 256, 0, stream>>>(
      hbuf, wff1T, bff1, nullptr, a1, 4096, 4096, 1024, 32);
  // out = a1 @ wff2T + bff2 + x2 (fp32)  (grid 16x64 = 1024)
  gemm_64<1, 0, 1, 0><<<1024, 256, 0, stream>>>(
      a1, wff2T, bff2, x2, (float*)d_out, 4096, 1024, 4096, 16);
}

// Round 17
// 235.230 us; speedup vs baseline: 1.0224x; 1.0224x over previous
//
#include <hip/hip_runtime.h>

#define DEV __device__ __forceinline__

typedef __attribute__((ext_vector_type(4))) float f32x4;
typedef __attribute__((ext_vector_type(8))) short short8;
typedef __attribute__((ext_vector_type(8))) __bf16 bf16x8;

DEV unsigned short f2bf(float f) {
  __bf16 h = (__bf16)f;
  return __builtin_bit_cast(unsigned short, h);
}
DEV unsigned pack2(float a, float b) {
  return (unsigned)f2bf(a) | ((unsigned)f2bf(b) << 16);
}
DEV bf16x8 ld_bf8(const unsigned short* p) {
  short8 v = *(const short8*)p;
  return __builtin_bit_cast(bf16x8, v);
}
DEV f32x4 MFMA(bf16x8 a, bf16x8 b, f32x4 c) {
  return __builtin_amdgcn_mfma_f32_16x16x32_bf16(a, b, c, 0, 0, 0);
}

typedef const __attribute__((address_space(1))) void GV;
typedef __attribute__((address_space(3))) void LV;
DEV void gl_lds16(const void* g, void* l) {
  __builtin_amdgcn_global_load_lds((GV*)g, (LV*)l, 16, 0, 0);
}

// 1D XCD-chunked swizzle (attention: head locality). Requires nwg % 8 == 0.
DEV void xcd_decode(int gx, int& bx, int& by) {
  const int nwg = gridDim.x, bid = blockIdx.x;
  const int cpx = nwg >> 3;
  const int swz = (bid & 7) * cpx + (bid >> 3);
  by = swz / gx;
  bx = swz % gx;
}

// 2D rectangular XCD chunks (GEMMs): XCD (r,c) owns blocks
// bx in [c*RX, (c+1)*RX), by in [r*RY, (r+1)*RY); x-major within so the
// round-resident {A-slice + B-slice} fits the 4MB per-XCD L2.
template<int RX, int RY, int RCOLS>
DEV void xcd_decode2(int& bx, int& by) {
  const int bid = blockIdx.x;
  const int xcd = bid & 7, local = bid >> 3;
  bx = (xcd % RCOLS) * RX + (local % RX);
  by = (xcd / RCOLS) * RY + (local / RX);
}

// ---------------- LayerNorm (fp32 in -> bf16 out), one row per block ----------
__global__ void __launch_bounds__(256) ln_fused(
    const float* __restrict__ x, const float* __restrict__ g,
    const float* __restrict__ b, unsigned short* __restrict__ y)
{
  const int row = blockIdx.x, tid = threadIdx.x;
  const float4 xv = ((const float4*)(x + (size_t)row * 1024))[tid];
  float s  = xv.x + xv.y + xv.z + xv.w;
  float s2 = xv.x * xv.x + xv.y * xv.y + xv.z * xv.z + xv.w * xv.w;
#pragma unroll
  for (int o = 32; o > 0; o >>= 1) { s += __shfl_down(s, o); s2 += __shfl_down(s2, o); }
  __shared__ float ps[4], ps2[4];
  if ((tid & 63) == 0) { ps[tid >> 6] = s; ps2[tid >> 6] = s2; }
  __syncthreads();
  float S  = ps[0] + ps[1] + ps[2] + ps[3];
  float S2 = ps2[0] + ps2[1] + ps2[2] + ps2[3];
  float mu = S * (1.f / 1024.f);
  float rs = rsqrtf(S2 * (1.f / 1024.f) - mu * mu + 1e-5f);
  const float4 gv = ((const float4*)g)[tid];
  const float4 bv = ((const float4*)b)[tid];
  uint2 r;
  r.x = pack2((xv.x - mu) * rs * gv.x + bv.x, (xv.y - mu) * rs * gv.y + bv.y);
  r.y = pack2((xv.z - mu) * rs * gv.z + bv.z, (xv.w - mu) * rs * gv.w + bv.w);
  ((uint2*)(y + (size_t)row * 1024))[tid] = r;
}

// ---------------- generic transpose fp32 [R][C] -> bf16 [C][R] ----------------
__global__ void __launch_bounds__(256) transp_f2b(
    const float* __restrict__ src, unsigned short* __restrict__ dst, int R, int C)
{
  __shared__ float t[64][65];
  const int c0 = blockIdx.x * 64, r0 = blockIdx.y * 64;
  const int tx = threadIdx.x & 63, tq = threadIdx.x >> 6;
#pragma unroll
  for (int i = 0; i < 16; i++) {
    int r = tq * 16 + i;
    t[r][tx] = src[(size_t)(r0 + r) * C + c0 + tx];
  }
  __syncthreads();
#pragma unroll
  for (int i = 0; i < 16; i++) {
    int c = tq * 16 + i;
    dst[(size_t)(c0 + c) * R + r0 + tx] = f2bf(t[tx][c]);
  }
}

// ------- wq/wk/wv [H][C][64] fp32 -> wqkvT [3*1024][1024] bf16 ([n][k]) -------
__global__ void __launch_bounds__(256) qkv_transp(
    const float* __restrict__ wq, const float* __restrict__ wk,
    const float* __restrict__ wv, unsigned short* __restrict__ dst)
{
  __shared__ float t[64][65];
  const int c0 = blockIdx.x * 64, h = blockIdx.y, z = blockIdx.z;
  const float* w = (z == 0 ? wq : z == 1 ? wk : wv) + (size_t)h * 1024 * 64;
  const int tx = threadIdx.x & 63, tq = threadIdx.x >> 6;
#pragma unroll
  for (int i = 0; i < 16; i++) {
    int c = tq * 16 + i;
    t[c][tx] = w[(size_t)(c0 + c) * 64 + tx];
  }
  __syncthreads();
  unsigned short* drow = dst + (size_t)(z * 1024 + h * 64) * 1024 + c0;
#pragma unroll
  for (int i = 0; i < 16; i++) {
    int d = tq * 16 + i;
    drow[(size_t)d * 1024 + tx] = f2bf(t[tx][d]);
  }
}

// ------- V section of qkv [4096][3072] -> vt [B*H][64][2048] (d-major) -------
__global__ void __launch_bounds__(256) v_transp(
    const unsigned short* __restrict__ qkv, unsigned short* __restrict__ vt)
{
  __shared__ unsigned s[64][65];
  const int t0 = blockIdx.x * 64, h = blockIdx.y, b = blockIdx.z;
  const int tx = threadIdx.x & 63, tq = threadIdx.x >> 6;
#pragma unroll
  for (int i = 0; i < 16; i++) {
    int tr = tq * 16 + i;
    s[tr][tx] = qkv[(size_t)(b * 2048 + t0 + tr) * 3072 + 2048 + h * 64 + tx];
  }
  __syncthreads();
  unsigned short* vb = vt + (size_t)((b * 16 + h) * 64) * 2048 + t0;
#pragma unroll
  for (int i = 0; i < 16; i++) {
    int d = tq * 16 + i;
    vb[(size_t)d * 2048 + tx] = (unsigned short)s[tx][d];
  }
}

// ---------------- GEMM 128x128, BK=32, dbuf 2-phase (r15), 2D XCD chunks ------
template<int BIAS, int RELU, int RES, int OBF, int RX, int RY, int RCOLS>
__global__ void __launch_bounds__(256) gemm_bt(
    const unsigned short* __restrict__ A, const unsigned short* __restrict__ Bt,
    const float* __restrict__ bias, const float* __restrict__ res,
    void* __restrict__ out, int M, int N, int K)
{
  __shared__ unsigned short As[2][128 * 32];
  __shared__ unsigned short Bs[2][128 * 32];
  int bx, by;
  xcd_decode2<RX, RY, RCOLS>(bx, by);
  const int tid = threadIdx.x;
  const int wid = tid >> 6, lane = tid & 63;
  const int lg = lane >> 4, lr = lane & 15;
  const int m0 = by * 128, n0 = bx * 128;
  const int wr = (wid >> 1) * 64, wc = (wid & 1) * 64;

  const int srow = tid >> 2;
  const int scs = (tid & 3) ^ (srow & 3);
  const unsigned short* ga = A + (size_t)(m0 + srow) * K + scs * 8;
  const unsigned short* gb = Bt + (size_t)(n0 + srow) * K + scs * 8;
  const int ca = (lg ^ (lr & 3)) * 8;

  f32x4 acc[4][4] = {};

  auto stage = [&](int buf, int k0) {
    char* asb = (char*)&As[buf][0] + wid * 1024;
    char* bsb = (char*)&Bs[buf][0] + wid * 1024;
    gl_lds16(ga + k0, asb);
    gl_lds16(ga + k0 + (size_t)64 * K, asb + 4096);
    gl_lds16(gb + k0, bsb);
    gl_lds16(gb + k0 + (size_t)64 * K, bsb + 4096);
  };

  stage(0, 0);
  int cur = 0;
  for (int k0 = 0; k0 < K; k0 += 32) {
    __syncthreads();
    if (k0 + 32 < K) stage(cur ^ 1, k0 + 32);
    bf16x8 a[4], b[4];
#pragma unroll
    for (int m = 0; m < 4; m++) a[m] = ld_bf8(&As[cur][(wr + m * 16 + lr) * 32 + ca]);
#pragma unroll
    for (int n = 0; n < 4; n++) b[n] = ld_bf8(&Bs[cur][(wc + n * 16 + lr) * 32 + ca]);
#pragma unroll
    for (int m = 0; m < 4; m++)
#pragma unroll
      for (int n = 0; n < 4; n++)
        acc[m][n] = MFMA(a[m], b[n], acc[m][n]);
    cur ^= 1;
  }

#pragma unroll
  for (int m = 0; m < 4; m++) {
    const int row0 = m0 + wr + m * 16 + lg * 4;
#pragma unroll
    for (int n = 0; n < 4; n++) {
      const int col = n0 + wc + n * 16 + lr;
      const float bv = BIAS ? bias[col] : 0.f;
#pragma unroll
      for (int r = 0; r < 4; r++) {
        const size_t off = (size_t)(row0 + r) * N + col;
        float v = acc[m][n][r] + bv;
        if (RES) v += res[off];
        if (RELU) v = v > 0.f ? v : 0.f;
        if (OBF) ((unsigned short*)out)[off] = f2bf(v);
        else     ((float*)out)[off] = v;
      }
    }
  }
}

// ---------------- GEMM 64x64, BK=64, dbuf, XOR-swizzled, 2D XCD chunks --------
template<int BIAS, int RELU, int RES, int OBF, int RX, int RY, int RCOLS>
__global__ void __launch_bounds__(256) gemm_64(
    const unsigned short* __restrict__ A, const unsigned short* __restrict__ Bt,
    const float* __restrict__ bias, const float* __restrict__ res,
    void* __restrict__ out, int M, int N, int K)
{
  __shared__ unsigned short As[2][64 * 64];
  __shared__ unsigned short Bs[2][64 * 64];
  int bx, by;
  xcd_decode2<RX, RY, RCOLS>(bx, by);
  const int tid = threadIdx.x;
  const int wid = tid >> 6, lane = tid & 63;
  const int lg = lane >> 4, lr = lane & 15;
  const int m0 = by * 64, n0 = bx * 64;
  const int wr = (wid >> 1) * 32, wc = (wid & 1) * 32;

  const int srow = tid >> 3;
  const int scs = (tid & 7) ^ (srow & 7);
  const unsigned short* ga = A + (size_t)(m0 + srow) * K + scs * 8;
  const unsigned short* gb = Bt + (size_t)(n0 + srow) * K + scs * 8;
  const int lxs = lr & 7;

  f32x4 acc[2][2] = {};

  auto stage = [&](int buf, int k0) {
    char* asb = (char*)&As[buf][0] + wid * 1024;
    char* bsb = (char*)&Bs[buf][0] + wid * 1024;
    gl_lds16(ga + k0, asb);
    gl_lds16(ga + k0 + (size_t)32 * K, asb + 4096);
    gl_lds16(gb + k0, bsb);
    gl_lds16(gb + k0 + (size_t)32 * K, bsb + 4096);
  };

  stage(0, 0);
  int cur = 0;
  for (int k0 = 0; k0 < K; k0 += 64) {
    __syncthreads();
    if (k0 + 64 < K) stage(cur ^ 1, k0 + 64);
#pragma unroll
    for (int kk = 0; kk < 2; kk++) {
      const int cb = kk * 4;
      bf16x8 a[2], b[2];
#pragma unroll
      for (int m = 0; m < 2; m++)
        a[m] = ld_bf8(&As[cur][(wr + m * 16 + lr) * 64 + ((cb + lg) ^ lxs) * 8]);
#pragma unroll
      for (int n = 0; n < 2; n++)
        b[n] = ld_bf8(&Bs[cur][(wc + n * 16 + lr) * 64 + ((cb + lg) ^ lxs) * 8]);
#pragma unroll
      for (int m = 0; m < 2; m++)
#pragma unroll
        for (int n = 0; n < 2; n++)
          acc[m][n] = MFMA(a[m], b[n], acc[m][n]);
    }
    cur ^= 1;
  }

#pragma unroll
  for (int m = 0; m < 2; m++) {
    const int row0 = m0 + wr + m * 16 + lg * 4;
#pragma unroll
    for (int n = 0; n < 2; n++) {
      const int col = n0 + wc + n * 16 + lr;
      const float bv = BIAS ? bias[col] : 0.f;
#pragma unroll
      for (int r = 0; r < 4; r++) {
        const size_t off = (size_t)(row0 + r) * N + col;
        float v = acc[m][n][r] + bv;
        if (RES) v += res[off];
        if (RELU) v = v > 0.f ? v : 0.f;
        if (OBF) ((unsigned short*)out)[off] = f2bf(v);
        else     ((float*)out)[off] = v;
      }
    }
  }
}

// ---------------- causal flash attention (fixed-shift softmax, r15) -----------
__global__ void __launch_bounds__(256) attn_fwd(
    const unsigned short* __restrict__ qkv, const unsigned short* __restrict__ vt,
    unsigned short* __restrict__ out)
{
  __shared__ unsigned short Ks[2][64 * 64];
  __shared__ unsigned short Vs[2][64 * 64];
  __shared__ unsigned short PA[4][16][72];
  __shared__ unsigned short PB[4][16][72];

  int j, bh;
  xcd_decode(16, j, bh);          // 4 heads per XCD (K/V L2-local)
  const int b = bh >> 4, h = bh & 15;
  const int tid = threadIdx.x, wid = tid >> 6, lane = tid & 63;
  const int lg = lane >> 4, lr = lane & 15;

  const int tA = j, tB = 31 - j;
  const int nkt = tB + 1;
  const float C2 = 0.18033688f;        // 0.125 * log2(e)

  const unsigned short* kbase = qkv + (size_t)(b * 2048) * 3072 + 1024 + h * 64;
  const unsigned short* vbase = vt + (size_t)(bh * 64) * 2048;

  const int sr = tid >> 3;
  const int sc = tid & 7;
  const int c0 = sc ^ (sr & 7);

  auto stage = [&](int buf, int kt) {
    const int kv0 = kt * 64;
    char* kd = (char*)&Ks[buf][0] + wid * 1024;
    char* vd = (char*)&Vs[buf][0] + wid * 1024;
    gl_lds16(kbase + (size_t)(kv0 + sr) * 3072 + c0 * 8, kd);
    gl_lds16(kbase + (size_t)(kv0 + 32 + sr) * 3072 + c0 * 8, kd + 4096);
    gl_lds16(vbase + (size_t)sr * 2048 + kv0 + c0 * 8, vd);
    gl_lds16(vbase + (size_t)(32 + sr) * 2048 + kv0 + c0 * 8, vd + 4096);
  };

  auto process = [&](int kt, int qt, const bf16x8& qf0, const bf16x8& qf1,
                     f32x4 (&o)[4], float& l, int buf, unsigned short* Pr) {
    const int kv0 = kt * 64;
    const int qg = qt * 64 + wid * 16 + lr;
    const unsigned short* Kb = &Ks[buf][0];
    const unsigned short* Vb = &Vs[buf][0];
    f32x4 s[4] = {};
    __builtin_amdgcn_s_setprio(1);
#pragma unroll
    for (int f = 0; f < 4; f++) {
      const int row = f * 16 + lr;
      const int rc = row & 7;
      s[f] = MFMA(ld_bf8(Kb + row * 64 + (lg ^ rc) * 8), qf0, s[f]);
      s[f] = MFMA(ld_bf8(Kb + row * 64 + ((lg | 4) ^ rc) * 8), qf1, s[f]);
    }
    __builtin_amdgcn_s_setprio(0);
    float p[16];
    const bool diag = (kt == qt);
    float ps = 0.f;
#pragma unroll
    for (int f = 0; f < 4; f++)
#pragma unroll
      for (int r = 0; r < 4; r++) {
        float sv = s[f][r];
        if (diag) {
          const int kv = kv0 + f * 16 + lg * 4 + r;
          sv = (kv <= qg) ? sv : -1e30f;
        }
        const float pv = exp2f(sv * C2);   // fixed-shift softmax numerator
        p[f * 4 + r] = pv;
        ps += pv;
      }
    l += ps;                               // lane-partial; reduced at epilogue
#pragma unroll
    for (int f = 0; f < 4; f++) {
      *(unsigned*)(Pr + f * 16 + lg * 4)     = pack2(p[f * 4 + 0], p[f * 4 + 1]);
      *(unsigned*)(Pr + f * 16 + lg * 4 + 2) = pack2(p[f * 4 + 2], p[f * 4 + 3]);
    }
    const bf16x8 pf0 = ld_bf8(Pr + lg * 8);
    const bf16x8 pf1 = ld_bf8(Pr + 32 + lg * 8);
    __builtin_amdgcn_s_setprio(1);
#pragma unroll
    for (int df = 0; df < 4; df++) {
      const int row = df * 16 + lr;
      const int rc = row & 7;
      o[df] = MFMA(ld_bf8(Vb + row * 64 + (lg ^ rc) * 8), pf0, o[df]);
      o[df] = MFMA(ld_bf8(Vb + row * 64 + ((lg | 4) ^ rc) * 8), pf1, o[df]);
    }
    __builtin_amdgcn_s_setprio(0);
  };

  const unsigned short* qb = qkv + (size_t)(b * 2048) * 3072 + h * 64;
  const int qrA = tA * 64 + wid * 16 + lr;
  const int qrB = tB * 64 + wid * 16 + lr;
  const bf16x8 qA0 = ld_bf8(qb + (size_t)qrA * 3072 + lg * 8);
  const bf16x8 qA1 = ld_bf8(qb + (size_t)qrA * 3072 + 32 + lg * 8);
  const bf16x8 qB0 = ld_bf8(qb + (size_t)qrB * 3072 + lg * 8);
  const bf16x8 qB1 = ld_bf8(qb + (size_t)qrB * 3072 + 32 + lg * 8);

  f32x4 oA[4] = {}, oB[4] = {};
  float lA = 0.f, lB = 0.f;

  stage(0, 0);
  __syncthreads();
  for (int kt = 0; kt < nkt; kt++) {
    const int buf = kt & 1;
    if (kt + 1 < nkt) stage(buf ^ 1, kt + 1);
    if (kt <= tA) process(kt, tA, qA0, qA1, oA, lA, buf, &PA[wid][lr][0]);
    process(kt, tB, qB0, qB1, oB, lB, buf, &PB[wid][lr][0]);
    __syncthreads();
  }

  lA += __shfl_xor(lA, 16); lA += __shfl_xor(lA, 32);
  lB += __shfl_xor(lB, 16); lB += __shfl_xor(lB, 32);
  const float invA = 1.f / lA, invB = 1.f / lB;
  {
    const int qg = tA * 64 + wid * 16 + lr;
    unsigned* orow = (unsigned*)(out + (size_t)(b * 2048 + qg) * 1024 + h * 64 + lg * 4);
#pragma unroll
    for (int df = 0; df < 4; df++) {
      orow[df * 8 + 0] = pack2(oA[df][0] * invA, oA[df][1] * invA);
      orow[df * 8 + 1] = pack2(oA[df][2] * invA, oA[df][3] * invA);
    }
  }
  {
    const int qg = tB * 64 + wid * 16 + lr;
    unsigned* orow = (unsigned*)(out + (size_t)(b * 2048 + qg) * 1024 + h * 64 + lg * 4);
#pragma unroll
    for (int df = 0; df < 4; df++) {
      orow[df * 8 + 0] = pack2(oB[df][0] * invB, oB[df][1] * invB);
      orow[df * 8 + 1] = pack2(oB[df][2] * invB, oB[df][3] * invB);
    }
  }
}

// ------------------------------------------------------------------------------
extern "C" void kernel_launch(void* const* d_in, const int* in_sizes, int n_in,
                              void* d_out, int out_size, void* d_ws, size_t ws_size,
                              hipStream_t stream)
{
  const float* x     = (const float*)d_in[0];
  const float* wq    = (const float*)d_in[1];
  const float* wk    = (const float*)d_in[2];
  const float* wv    = (const float*)d_in[3];
  const float* wproj = (const float*)d_in[4];
  const float* bproj = (const float*)d_in[5];
  const float* gln1  = (const float*)d_in[6];
  const float* bln1  = (const float*)d_in[7];
  const float* gln2  = (const float*)d_in[8];
  const float* bln2  = (const float*)d_in[9];
  const float* wff1  = (const float*)d_in[10];
  const float* bff1  = (const float*)d_in[11];
  const float* wff2  = (const float*)d_in[12];
  const float* bff2  = (const float*)d_in[13];

  char* ws = (char*)d_ws;
  const size_t MB = 1u << 20;
  float*          x2    = (float*)         (ws + 0 * MB);   // 16 MB
  unsigned short* hbuf  = (unsigned short*)(ws + 16 * MB);  //  8 MB
  unsigned short* xn1   = (unsigned short*)(ws + 24 * MB);  //  8 MB (reused by attn out)
  unsigned short* attn  = (unsigned short*)(ws + 24 * MB);
  unsigned short* qkvb  = (unsigned short*)(ws + 32 * MB);  // 24 MB
  unsigned short* vtb   = (unsigned short*)(ws + 56 * MB);  //  8 MB
  unsigned short* a1    = (unsigned short*)(ws + 32 * MB);  // 32 MB (over dead qkv+vt)
  unsigned short* wqkvT = (unsigned short*)(ws + 64 * MB);  //  6 MB
  unsigned short* wprojT= (unsigned short*)(ws + 70 * MB);  //  2 MB
  unsigned short* wff1T = (unsigned short*)(ws + 72 * MB);  //  8 MB
  unsigned short* wff2T = (unsigned short*)(ws + 80 * MB);  //  8 MB  (total 88 MB)

  // weight preprocessing (fp32 -> bf16, transposed to [N][K])
  qkv_transp<<<dim3(16, 16, 3), 256, 0, stream>>>(wq, wk, wv, wqkvT);
  transp_f2b<<<dim3(16, 16), 256, 0, stream>>>(wproj, wprojT, 1024, 1024);
  transp_f2b<<<dim3(64, 16), 256, 0, stream>>>(wff1, wff1T, 1024, 4096);
  transp_f2b<<<dim3(16, 64), 256, 0, stream>>>(wff2, wff2T, 4096, 1024);

  // x -> LN1 -> xn1 (bf16)
  ln_fused<<<4096, 256, 0, stream>>>(x, gln1, bln1, xn1);
  // QKV = xn1 @ wqkvT : [4096][3072] bf16  (grid 24x32; XCD rects 12x8, 2 cols)
  gemm_bt<0, 0, 0, 1, 12, 8, 2><<<768, 256, 0, stream>>>(
      xn1, wqkvT, nullptr, nullptr, qkvb, 4096, 3072, 1024);
  // V -> d-major
  v_transp<<<dim3(32, 16, 2), 256, 0, stream>>>(qkvb, vtb);
  // attention -> attn (bf16 [4096][1024])  (grid 512, diagonal-paired)
  attn_fwd<<<512, 256, 0, stream>>>(qkvb, vtb, attn);
  // x2 = attn @ wprojT + bproj + x  (fp32)  (grid 16x64; rects 8x16, 2 cols)
  gemm_64<1, 0, 1, 0, 8, 16, 2><<<1024, 256, 0, stream>>>(
      attn, wprojT, bproj, x, x2, 4096, 1024, 1024);
  // h = LN2(x2) (bf16)
  ln_fused<<<4096, 256, 0, stream>>>(x2, gln2, bln2, hbuf);
  // a1 = relu(h @ wff1T + bff1)  (bf16)  (grid 32x32; rects 8x16, 4 cols)
  gemm_bt<1, 1, 0, 1, 8, 16, 4><<<1024, 256, 0, stream>>>(
      hbuf, wff1T, bff1, nullptr, a1, 4096, 4096, 1024);
  // out = a1 @ wff2T + bff2 + x2 (fp32)  (grid 16x64; rects 8x16, 2 cols)
  gemm_64<1, 0, 1, 0, 8, 16, 2><<<1024, 256, 0, stream>>>(
      a1, wff2T, bff2, x2, (float*)d_out, 4096, 1024, 4096);
}